// Round 20
// baseline (267.182 us; speedup 1.0000x reference)
//
#include <hip/hip_runtime.h>
#include <hip/hip_bf16.h>

#define NROW 8192
#define DIM  256
#define SPLIT 16
#define ROWS_PER (NROW / SPLIT)   // 512 rows per colmax block

typedef float  f32x4  __attribute__((ext_vector_type(4)));
typedef __bf16 bf16x8 __attribute__((ext_vector_type(8)));

__device__ __forceinline__ unsigned int rne_bf16(float x) {
    unsigned int u = __builtin_bit_cast(unsigned int, x);
    return (u + 0x7fffu + ((u >> 16) & 1u)) >> 16;
}

// f32 -> bf16 (RNE), 8 elems/thread
__global__ __launch_bounds__(256) void convert_kernel(const float* __restrict__ src,
                                                      unsigned short* __restrict__ dst) {
    size_t i = ((size_t)blockIdx.x * 256 + threadIdx.x) * 8;
    float4 a = *(const float4*)(src + i);
    float4 b = *(const float4*)(src + i + 4);
    uint4 o;
    o.x = rne_bf16(a.x) | (rne_bf16(a.y) << 16);
    o.y = rne_bf16(a.z) | (rne_bf16(a.w) << 16);
    o.z = rne_bf16(b.x) | (rne_bf16(b.y) << 16);
    o.w = rne_bf16(b.z) | (rne_bf16(b.w) << 16);
    *(uint4*)(dst + i) = o;
}

// exact f32 diagonal: one wave per row
__global__ __launch_bounds__(256) void diag_kernel(const float* __restrict__ m,
                                                   const float* __restrict__ q,
                                                   float* __restrict__ diag) {
    int row  = blockIdx.x * 4 + (threadIdx.x >> 6);
    int lane = threadIdx.x & 63;
    const float4* mr = (const float4*)(m + (size_t)row * DIM);
    const float4* qr = (const float4*)(q + (size_t)row * DIM);
    float4 a = mr[lane];
    float4 b = qr[lane];
    float d = a.x * b.x + a.y * b.y + a.z * b.z + a.w * b.w;
    #pragma unroll
    for (int o = 32; o > 0; o >>= 1) d += __shfl_down(d, o, 64);
    if (lane == 0) diag[row] = d;
}

// colmax: scores[i][j] = dot(m[i,:], q[j,:]); per-column (j) max over a row split.
// Wave holds q-fragments (16 cols x K=256) in registers; loops over row tiles.
// MFMA D layout (verified, learn_hip m89): col = lane&15, row = (lane>>4)*4 + reg.
__global__ __launch_bounds__(256) void colmax_kernel(const unsigned short* __restrict__ mb,
                                                     const unsigned short* __restrict__ qb,
                                                     float* __restrict__ partial) {
    int tid  = threadIdx.x;
    int wave = tid >> 6;
    int lane = tid & 63;
    int l15  = lane & 15;
    int lg   = lane >> 4;          // k-group 0..3
    int j0   = blockIdx.x * 64 + wave * 16;

    // B fragments: B[k][col] = q[col][k]; lane reads q[j0+l15][lg*8 + f*32 .. +8]
    const unsigned short* qp = qb + (size_t)(j0 + l15) * DIM + lg * 8;
    bf16x8 b[8];
    #pragma unroll
    for (int f = 0; f < 8; ++f)
        b[f] = *reinterpret_cast<const bf16x8*>(qp + f * 32);

    int i0 = blockIdx.y * ROWS_PER;
    const unsigned short* ap = mb + (size_t)(i0 + l15) * DIM + lg * 8;

    float cmax = -3.4e38f;
    for (int it = 0; it < ROWS_PER / 16; ++it) {
        bf16x8 a[8];
        #pragma unroll
        for (int f = 0; f < 8; ++f)
            a[f] = *reinterpret_cast<const bf16x8*>(ap + f * 32);
        ap += 16 * DIM;
        f32x4 c0 = {0.f, 0.f, 0.f, 0.f};
        f32x4 c1 = {0.f, 0.f, 0.f, 0.f};
        #pragma unroll
        for (int f = 0; f < 8; f += 2) {
            c0 = __builtin_amdgcn_mfma_f32_16x16x32_bf16(a[f],     b[f],     c0, 0, 0, 0);
            c1 = __builtin_amdgcn_mfma_f32_16x16x32_bf16(a[f + 1], b[f + 1], c1, 0, 0, 0);
        }
        f32x4 s = c0 + c1;
        cmax = fmaxf(cmax, fmaxf(fmaxf(s[0], s[1]), fmaxf(s[2], s[3])));
    }
    // combine the 4 lane groups holding the same column
    cmax = fmaxf(cmax, __shfl_xor(cmax, 16, 64));
    cmax = fmaxf(cmax, __shfl_xor(cmax, 32, 64));
    if (lg == 0)
        partial[(size_t)blockIdx.y * NROW + j0 + l15] = cmax;
}

__global__ __launch_bounds__(256) void finalize_kernel(const float* __restrict__ partial,
                                                       const float* __restrict__ diag,
                                                       const float* __restrict__ labels,
                                                       float* __restrict__ out) {
    __shared__ float red[4];
    int tid = threadIdx.x;
    float sum = 0.f;
    for (int j = tid; j < NROW; j += 256) {
        float mx = -3.4e38f;
        #pragma unroll
        for (int s = 0; s < SPLIT; ++s) mx = fmaxf(mx, partial[(size_t)s * NROW + j]);
        float t = (mx == labels[j]) ? 1.0f : -1.0f;
        sum += fmaxf(0.f, -t * (mx - diag[j]));
    }
    #pragma unroll
    for (int o = 32; o > 0; o >>= 1) sum += __shfl_down(sum, o, 64);
    if ((tid & 63) == 0) red[tid >> 6] = sum;
    __syncthreads();
    if (tid == 0) out[0] = (red[0] + red[1] + red[2] + red[3]) / (float)NROW;
}

extern "C" void kernel_launch(void* const* d_in, const int* in_sizes, int n_in,
                              void* d_out, int out_size, void* d_ws, size_t ws_size,
                              hipStream_t stream) {
    const float* m      = (const float*)d_in[0];
    const float* q      = (const float*)d_in[1];
    const float* labels = (const float*)d_in[2];
    float* out = (float*)d_out;

    // workspace layout
    unsigned short* mb = (unsigned short*)d_ws;                 // N*D bf16 = 4 MB
    unsigned short* qb = mb + (size_t)NROW * DIM;               // 4 MB
    float* diag    = (float*)(qb + (size_t)NROW * DIM);         // 32 KB
    float* partial = diag + NROW;                               // SPLIT*N*4 = 512 KB
    size_t needed = (size_t)NROW * DIM * 4 + NROW * 4 + (size_t)SPLIT * NROW * 4;
    if (ws_size < needed) return;

    int conv_blocks = (NROW * DIM) / (256 * 8);                 // 1024
    convert_kernel<<<conv_blocks, 256, 0, stream>>>(m, mb);
    convert_kernel<<<conv_blocks, 256, 0, stream>>>(q, qb);
    diag_kernel<<<NROW / 4, 256, 0, stream>>>(m, q, diag);
    colmax_kernel<<<dim3(NROW / 64, SPLIT), 256, 0, stream>>>(mb, qb, partial);
    finalize_kernel<<<1, 256, 0, stream>>>(partial, diag, labels, out);
}